// Round 1
// baseline (497.741 us; speedup 1.0000x reference)
//
#include <hip/hip_runtime.h>

// Problem constants (fixed by reference: B=4,S=4096,IN=1024,OUT=4096,RANK=32)
#define B_DIM 4
#define S_DIM 4096
#define IN_DIM 1024
#define OUT_DIM 4096
#define RANK_DIM 32

#define M_DIM (B_DIM * S_DIM)   // 16384
#define N_DIM OUT_DIM           // 4096
#define K_DIM IN_DIM            // 1024

#define CVT_BLOCKS ((M_DIM * K_DIM) / 1024)  // 16384 blocks for x-cast

typedef _Float16 h4 __attribute__((ext_vector_type(4)));
typedef _Float16 h8 __attribute__((ext_vector_type(8)));
typedef float f32x16 __attribute__((ext_vector_type(16)));

// Async global->LDS, 16B per lane. LDS dest = wave-uniform base + lane*16.
__device__ __forceinline__ void async_load16(const void* g, void* l) {
  __builtin_amdgcn_global_load_lds((const __attribute__((address_space(1))) void*)g,
                                   (__attribute__((address_space(3))) void*)l,
                                   16, 0, 0);
}

// ---------------------------------------------------------------------------
// Fused prep (unchanged from prior round — ~20-30 us, not the bottleneck):
// blocks [0, CVT_BLOCKS) cast x fp32->f16; blocks [CVT_BLOCKS, +OUT_DIM)
// build one row of w_eff = weight + w1[src] @ w2[tgt], cast to f16.
// ---------------------------------------------------------------------------
__global__ __launch_bounds__(256) void prep_fused_kernel(
    const float4* __restrict__ x, h4* __restrict__ xh,
    const float* __restrict__ weight, const float* __restrict__ w1,
    const float* __restrict__ w2, const int* __restrict__ src_id,
    const int* __restrict__ tgt_id, h4* __restrict__ weff) {
  if (blockIdx.x < CVT_BLOCKS) {
    const int i = blockIdx.x * 256 + threadIdx.x;
    const float4 v = x[i];
    h4 o;
    o[0] = (_Float16)v.x; o[1] = (_Float16)v.y;
    o[2] = (_Float16)v.z; o[3] = (_Float16)v.w;
    xh[i] = o;
  } else {
    const int n = blockIdx.x - CVT_BLOCKS;    // 0..4095
    const int src = src_id[0];
    const int tgt = tgt_id[0];
    __shared__ float w1r[RANK_DIM];
    if (threadIdx.x < RANK_DIM)
      w1r[threadIdx.x] = w1[((size_t)src * OUT_DIM + n) * RANK_DIM + threadIdx.x];
    __syncthreads();
    const int k4 = threadIdx.x;               // 0..255 (= IN/4)
    float4 acc = ((const float4*)(weight + (size_t)n * IN_DIM))[k4];
    const float* w2t = w2 + (size_t)tgt * RANK_DIM * IN_DIM;
#pragma unroll 8
    for (int r = 0; r < RANK_DIM; ++r) {
      const float4 wv = ((const float4*)(w2t + (size_t)r * IN_DIM))[k4];
      const float c = w1r[r];
      acc.x += c * wv.x; acc.y += c * wv.y; acc.z += c * wv.z; acc.w += c * wv.w;
    }
    h4 o;
    o[0] = (_Float16)acc.x; o[1] = (_Float16)acc.y;
    o[2] = (_Float16)acc.z; o[3] = (_Float16)acc.w;
    weff[(size_t)n * (IN_DIM / 4) + k4] = o;
  }
}

// ---------------------------------------------------------------------------
// 256x256 8-phase GEMM (T1+T2+T3+T4+T5 port of the learn_hip m201 template):
// 8 waves (2M x 4N), per-wave 128x64 output as acc[4 phases][2] of 32x32 frags.
// BK=64, double-buffered in 4 distinct __shared__ arrays (compile-time buffer
// selection via 2x-unrolled K loop). Per K-tile: 4 phases of
// {ds_read subtile | phase0: prefetch next tile (8x global_load_lds) + B-frags
//  -> s_barrier -> setprio(1) -> 8x mfma_32x32x16 -> setprio(0) -> s_barrier}.
// Only vmcnt(0) at the tile boundary (loads issued ~3.5 phases earlier).
// LDS 16B-column XOR swizzle by row&7 applied on the GLOBAL source column
// (global_load_lds LDS dest is fixed base+lane*16) — 4-way residual conflict,
// structural minimum for 128B rows.
// ---------------------------------------------------------------------------
__device__ __forceinline__ void ktile_body(
    const _Float16* cA, const _Float16* cB,   // current LDS buffers (read)
    _Float16* nA, _Float16* nB,               // next LDS buffers (prefetch dest)
    const _Float16* gA0, const _Float16* gB0, // per-thread swizzled global bases
    int kNext, bool doStage, int wave,
    int aBase, int bBase, int kq, int key,
    f32x16 (&acc)[4][2]) {
  h8 b0[4], b1[4], a[4];
  // Phase 0 ds_reads: all 8 B-frags (reused by all 4 phases) + 4 A-frags.
#pragma unroll
  for (int ks = 0; ks < 4; ++ks) {
    const int co = (((ks * 2 + kq) ^ key) << 3);
    b0[ks] = *(const h8*)&cB[bBase + co];
    b1[ks] = *(const h8*)&cB[bBase + 2048 + co];
    a[ks]  = *(const h8*)&cA[aBase + co];
  }
  // Prefetch next K-tile into the other buffer: 8 per-thread loads, in flight
  // across the whole tile's compute (~3.5 phases of latency cover).
  if (doStage) {
#pragma unroll
    for (int i = 0; i < 4; ++i) {
      async_load16(gA0 + (size_t)i * 64 * K_DIM + kNext, nA + i * 4096 + wave * 512);
      async_load16(gB0 + (size_t)i * 64 * K_DIM + kNext, nB + i * 4096 + wave * 512);
    }
  }
  __builtin_amdgcn_s_barrier();
  __builtin_amdgcn_s_setprio(1);
#pragma unroll
  for (int ks = 0; ks < 4; ++ks) {
    acc[0][0] = __builtin_amdgcn_mfma_f32_32x32x16_f16(a[ks], b0[ks], acc[0][0], 0, 0, 0);
    acc[0][1] = __builtin_amdgcn_mfma_f32_32x32x16_f16(a[ks], b1[ks], acc[0][1], 0, 0, 0);
  }
  __builtin_amdgcn_s_setprio(0);
  __builtin_amdgcn_s_barrier();
  // Phases 1..3: 4 A-frag reads + 8 MFMA each, barrier-sandwiched.
#pragma unroll
  for (int p = 1; p < 4; ++p) {
    h8 ap[4];
#pragma unroll
    for (int ks = 0; ks < 4; ++ks)
      ap[ks] = *(const h8*)&cA[aBase + p * 2048 + (((ks * 2 + kq) ^ key) << 3)];
    __builtin_amdgcn_s_barrier();
    __builtin_amdgcn_s_setprio(1);
#pragma unroll
    for (int ks = 0; ks < 4; ++ks) {
      acc[p][0] = __builtin_amdgcn_mfma_f32_32x32x16_f16(ap[ks], b0[ks], acc[p][0], 0, 0, 0);
      acc[p][1] = __builtin_amdgcn_mfma_f32_32x32x16_f16(ap[ks], b1[ks], acc[p][1], 0, 0, 0);
    }
    __builtin_amdgcn_s_setprio(0);
    if (p < 3) __builtin_amdgcn_s_barrier();
  }
  // Tile boundary: my prefetch loads must have landed before ANY wave reads
  // the next buffer -> per-wave vmcnt(0), then collective barrier.
  asm volatile("s_waitcnt vmcnt(0)" ::: "memory");
  __builtin_amdgcn_s_barrier();
}

__global__ __launch_bounds__(512, 2) void lms_gemm256_kernel(
    const _Float16* __restrict__ A,   // [M][K] f16
    const _Float16* __restrict__ Bt,  // [N][K] f16
    const float* __restrict__ bias,   // [N]
    float* __restrict__ C) {          // [M][N]
  // 4 distinct buffers (128 KiB total) so the compiler can prove
  // prefetch-writes never alias current-tile reads.
  __shared__ _Float16 sA0[256 * 64];
  __shared__ _Float16 sA1[256 * 64];
  __shared__ _Float16 sB0[256 * 64];
  __shared__ _Float16 sB1[256 * 64];

  const int tid = threadIdx.x;
  const int wave = tid >> 6;
  const int lane = tid & 63;

  // XCD-aware bijective swizzle (1024 wg % 8 == 0), then bm-major grouping:
  // each XCD owns 8 A-panels x all 16 B-panels (L2/LLC locality).
  const int bid = blockIdx.x;                 // 0..1023
  const int wg = (bid & 7) * 128 + (bid >> 3);
  const int bm = wg >> 4;                     // 0..63
  const int bn = wg & 15;                     // 0..15

  const int wr = wave >> 2;                   // 0..1  (M half)
  const int wc = wave & 3;                    // 0..3  (N quarter)
  const int fr = lane & 31;
  const int kq = lane >> 5;                   // which 8-half k-group
  const int key = fr & 7;                     // swizzle key (= row&7)
  const int aBase = (wr * 128 + fr) * 64;     // halfs; phase adds p*2048
  const int bBase = (wc * 64 + fr) * 64;      // halfs; ni adds 2048

  // Staging: thread tid covers LDS halfs [chunk*4096 + tid*8, +8):
  // row = chunk*64 + tid/8, 16B-block = tid&7 holding global block
  // (tid&7) ^ (row&7)  -> swizzle applied on the global source column.
  const int srow = tid >> 3;                  // 0..63
  const int sblk = (tid & 7) ^ (srow & 7);
  const _Float16* gA0 = A  + (size_t)(bm * 256 + srow) * K_DIM + sblk * 8;
  const _Float16* gB0 = Bt + (size_t)(bn * 256 + srow) * K_DIM + sblk * 8;

  f32x16 acc[4][2] = {};

  // Prologue: stage K-tile 0 into buffer 0, drain, sync.
#pragma unroll
  for (int i = 0; i < 4; ++i) {
    async_load16(gA0 + (size_t)i * 64 * K_DIM, sA0 + i * 4096 + wave * 512);
    async_load16(gB0 + (size_t)i * 64 * K_DIM, sB0 + i * 4096 + wave * 512);
  }
  asm volatile("s_waitcnt vmcnt(0)" ::: "memory");
  __builtin_amdgcn_s_barrier();

  // 16 K-tiles, 2 per iteration with compile-time buffer roles.
  for (int tt = 0; tt < 16; tt += 2) {
    ktile_body(sA0, sB0, sA1, sB1, gA0, gB0, (tt + 1) * 64, true,
               wave, aBase, bBase, kq, key, acc);
    ktile_body(sA1, sB1, sA0, sB0, gA0, gB0, (tt + 2) * 64, (tt + 2) < 16,
               wave, aBase, bBase, kq, key, acc);
  }

  // Epilogue: 32x32 C/D layout col = lane&31,
  // row = (reg&3) + 8*(reg>>2) + 4*(lane>>5)   [m74/m101, verified passing]
  const int cn = fr;
  const int rq = (lane >> 5) * 4;
#pragma unroll
  for (int ni = 0; ni < 2; ++ni) {
    const int col = bn * 256 + wc * 64 + ni * 32 + cn;
    const float bv = bias[col];
#pragma unroll
    for (int p = 0; p < 4; ++p) {
      const int rowb = bm * 256 + wr * 128 + p * 32 + rq;
      float* cp = C + (size_t)rowb * N_DIM + col;
#pragma unroll
      for (int reg = 0; reg < 16; ++reg) {
        const int roff = (reg & 3) + 8 * (reg >> 2);
        cp[(size_t)roff * N_DIM] = acc[p][ni][reg] + bv;
      }
    }
  }
}

extern "C" void kernel_launch(void* const* d_in, const int* in_sizes, int n_in,
                              void* d_out, int out_size, void* d_ws, size_t ws_size,
                              hipStream_t stream) {
  const float* x      = (const float*)d_in[0];  // [4,4096,1024]
  const float* weight = (const float*)d_in[1];  // [4096,1024]
  const float* bias   = (const float*)d_in[2];  // [4096]
  const float* w1     = (const float*)d_in[3];  // [9,4096,32]
  const float* w2     = (const float*)d_in[4];  // [9,32,1024]
  const int* src_id   = (const int*)d_in[5];    // scalar
  const int* tgt_id   = (const int*)d_in[6];    // scalar
  float* out          = (float*)d_out;          // [4,4096,4096]

  // Workspace layout: x_f16 (32 MiB) | w_eff_f16 (8 MiB). Rewritten fully
  // every call (harness re-poisons d_ws).
  _Float16* xh   = (_Float16*)d_ws;
  _Float16* weff = xh + (size_t)M_DIM * K_DIM;

  prep_fused_kernel<<<CVT_BLOCKS + N_DIM, 256, 0, stream>>>(
      (const float4*)x, (h4*)xh, weight, w1, w2, src_id, tgt_id, (h4*)weff);

  lms_gemm256_kernel<<<dim3(1024), dim3(512), 0, stream>>>(xh, weff, bias, out);
}

// Round 2
// 485.364 us; speedup vs baseline: 1.0255x; 1.0255x over previous
//
#include <hip/hip_runtime.h>

// Problem constants (fixed by reference: B=4,S=4096,IN=1024,OUT=4096,RANK=32)
#define B_DIM 4
#define S_DIM 4096
#define IN_DIM 1024
#define OUT_DIM 4096
#define RANK_DIM 32

#define M_DIM (B_DIM * S_DIM)   // 16384
#define N_DIM OUT_DIM           // 4096
#define K_DIM IN_DIM            // 1024

#define CVT_BLOCKS ((M_DIM * K_DIM) / 1024)  // 16384 blocks for x-cast

typedef _Float16 h4 __attribute__((ext_vector_type(4)));
typedef _Float16 h8 __attribute__((ext_vector_type(8)));
typedef float f32x16 __attribute__((ext_vector_type(16)));

// Async global->LDS, 16B per lane. LDS dest = wave-uniform base + lane*16.
__device__ __forceinline__ void async_load16(const void* g, void* l) {
  __builtin_amdgcn_global_load_lds((const __attribute__((address_space(1))) void*)g,
                                   (__attribute__((address_space(3))) void*)l,
                                   16, 0, 0);
}

// ---------------------------------------------------------------------------
// Fused prep (unchanged; ~25 us, not the bottleneck):
// blocks [0, CVT_BLOCKS) cast x fp32->f16; blocks [CVT_BLOCKS, +OUT_DIM)
// build one row of w_eff = weight + w1[src] @ w2[tgt], cast to f16.
// ---------------------------------------------------------------------------
__global__ __launch_bounds__(256) void prep_fused_kernel(
    const float4* __restrict__ x, h4* __restrict__ xh,
    const float* __restrict__ weight, const float* __restrict__ w1,
    const float* __restrict__ w2, const int* __restrict__ src_id,
    const int* __restrict__ tgt_id, h4* __restrict__ weff) {
  if (blockIdx.x < CVT_BLOCKS) {
    const int i = blockIdx.x * 256 + threadIdx.x;
    const float4 v = x[i];
    h4 o;
    o[0] = (_Float16)v.x; o[1] = (_Float16)v.y;
    o[2] = (_Float16)v.z; o[3] = (_Float16)v.w;
    xh[i] = o;
  } else {
    const int n = blockIdx.x - CVT_BLOCKS;    // 0..4095
    const int src = src_id[0];
    const int tgt = tgt_id[0];
    __shared__ float w1r[RANK_DIM];
    if (threadIdx.x < RANK_DIM)
      w1r[threadIdx.x] = w1[((size_t)src * OUT_DIM + n) * RANK_DIM + threadIdx.x];
    __syncthreads();
    const int k4 = threadIdx.x;               // 0..255 (= IN/4)
    float4 acc = ((const float4*)(weight + (size_t)n * IN_DIM))[k4];
    const float* w2t = w2 + (size_t)tgt * RANK_DIM * IN_DIM;
#pragma unroll 8
    for (int r = 0; r < RANK_DIM; ++r) {
      const float4 wv = ((const float4*)(w2t + (size_t)r * IN_DIM))[k4];
      const float c = w1r[r];
      acc.x += c * wv.x; acc.y += c * wv.y; acc.z += c * wv.z; acc.w += c * wv.w;
    }
    h4 o;
    o[0] = (_Float16)acc.x; o[1] = (_Float16)acc.y;
    o[2] = (_Float16)acc.z; o[3] = (_Float16)acc.w;
    weff[(size_t)n * (IN_DIM / 4) + k4] = o;
  }
}

// ---------------------------------------------------------------------------
// 256x256 GEMM, quad-buffered BK=32, depth-3 counted-vmcnt pipeline.
// 8 waves (2M x 4N), per-wave 128x64 output = acc[4][2] of 32x32 frags.
// Body t: {issue T(t+3) loads (4/thread) | ds_read 12xb128 | 16 MFMA |
//          s_waitcnt vmcnt(8) lgkmcnt(0); s_barrier}  -- ONE barrier/tile,
// never vmcnt(0) in steady state (m218 lesson: counted-vs-drain0 = +38-73%).
// lgkmcnt(0) in the combined wait makes issue-at-top WAR-safe: all ds_reads
// of the buffer about to be overwritten have RETURNED before any wave passes
// the barrier. Wait+barrier fused in one asm so nothing slides between.
// LDS swizzle for BK=32 (4x16B blocks/row): block ^= (row>>1)&3, applied on
// the GLOBAL source column (global_load_lds dest is linear). Bank math:
// bank = 16*(row&1) + 4*(blk^((row>>1)&3)) -> 8 distinct 4-bank sets per
// 8-row period -> 4-way residual (same as the BK=64 row&7 scheme).
// ---------------------------------------------------------------------------
__global__ __launch_bounds__(512, 2) void lms_gemm256_kernel(
    const _Float16* __restrict__ A,   // [M][K] f16
    const _Float16* __restrict__ Bt,  // [N][K] f16
    const float* __restrict__ bias,   // [N]
    float* __restrict__ C) {          // [M][N]
  __shared__ _Float16 sA[4][8192];    // 4 x 256rows x 32halfs = 64 KiB
  __shared__ _Float16 sB[4][8192];    // 64 KiB

  const int tid = threadIdx.x;
  const int wave = tid >> 6;
  const int lane = tid & 63;

  // XCD-aware bijective swizzle (1024 wg, 8 XCDs): each XCD gets 8 bm x 16 bn.
  const int bid = blockIdx.x;                 // 0..1023
  const int wg = (bid & 7) * 128 + (bid >> 3);
  const int bm = wg >> 4;                     // 0..63
  const int bn = wg & 15;                     // 0..15

  const int wr = wave >> 2;                   // 0..1  (M half)
  const int wc = wave & 3;                    // 0..3  (N quarter)
  const int fr = lane & 31;
  const int kq = lane >> 5;                   // which 16B k-block within kstep
  const int key = (fr >> 1) & 3;              // read-side swizzle key
  const int aBase = (wr * 128 + fr) * 32;     // halfs; +mi*1024
  const int bBase = (wc * 64 + fr) * 32;      // halfs; +ni*1024
  const int bo0 = (kq ^ key) << 3;            // ks=0 block offset (halfs)
  const int bo1 = bo0 ^ 16;                   // ks=1 (= block^2)

  // Staging: per tile, A = 256rows x 32halfs = 1024 16B-units = 2 rounds of
  // 512 threads. Thread: row = round*128 + wave*16 + lane/4,
  // lds blk = lane&3, global blk = (lane&3) ^ ((row>>1)&3) = (lane&3)^((lane>>3)&3).
  const int srow = wave * 16 + (lane >> 2);
  const int sblk = (lane & 3) ^ ((lane >> 3) & 3);
  const _Float16* gA = A + (size_t)(bm * 256 + srow) * K_DIM + sblk * 8;
  const _Float16* gB = Bt + (size_t)(bn * 256 + srow) * K_DIM + sblk * 8;

  f32x16 acc[4][2] = {};

#define STAGE_TILE(nA, nB, KOFF)                                              \
  {                                                                           \
    async_load16(gA + (KOFF), (nA) + wave * 512);                             \
    async_load16(gA + (KOFF) + 128 * K_DIM, (nA) + 4096 + wave * 512);        \
    async_load16(gB + (KOFF), (nB) + wave * 512);                             \
    async_load16(gB + (KOFF) + 128 * K_DIM, (nB) + 4096 + wave * 512);        \
  }

#define KBODY(cA, cB, nA, nB, DO_STAGE, KOFF, WAITBAR)                        \
  {                                                                           \
    if (DO_STAGE) STAGE_TILE(nA, nB, KOFF);                                   \
    h8 af[4][2], bf[2][2];                                                    \
    _Pragma("unroll") for (int mi = 0; mi < 4; ++mi) {                        \
      af[mi][0] = *(const h8*)&(cA)[aBase + mi * 1024 + bo0];                 \
      af[mi][1] = *(const h8*)&(cA)[aBase + mi * 1024 + bo1];                 \
    }                                                                         \
    _Pragma("unroll") for (int ni = 0; ni < 2; ++ni) {                        \
      bf[ni][0] = *(const h8*)&(cB)[bBase + ni * 1024 + bo0];                 \
      bf[ni][1] = *(const h8*)&(cB)[bBase + ni * 1024 + bo1];                 \
    }                                                                         \
    __builtin_amdgcn_s_setprio(1);                                            \
    _Pragma("unroll") for (int ks = 0; ks < 2; ++ks)                          \
      _Pragma("unroll") for (int mi = 0; mi < 4; ++mi)                        \
        _Pragma("unroll") for (int ni = 0; ni < 2; ++ni)                      \
          acc[mi][ni] = __builtin_amdgcn_mfma_f32_32x32x16_f16(               \
              af[mi][ks], bf[ni][ks], acc[mi][ni], 0, 0, 0);                  \
    __builtin_amdgcn_s_setprio(0);                                            \
    WAITBAR;                                                                  \
  }

#define WB8 asm volatile("s_waitcnt vmcnt(8) lgkmcnt(0)\ns_barrier" ::: "memory")
#define WB4 asm volatile("s_waitcnt vmcnt(4) lgkmcnt(0)\ns_barrier" ::: "memory")
#define WB0 asm volatile("s_waitcnt vmcnt(0) lgkmcnt(0)\ns_barrier" ::: "memory")

  // Prologue: stage T0,T1,T2 (12 loads); wait for T0 only; rendezvous.
  STAGE_TILE(sA[0], sB[0], 0);
  STAGE_TILE(sA[1], sB[1], 32);
  STAGE_TILE(sA[2], sB[2], 64);
  asm volatile("s_waitcnt vmcnt(8)\ns_barrier" ::: "memory");

  // Bodies t=0..27 (stage T(t+3)); steady-state outstanding = 12, wait to 8.
  for (int t = 0; t < 28; t += 4) {
    const int ko = t * 32;
    KBODY(sA[0], sB[0], sA[3], sB[3], true, ko + 96,  WB8);
    KBODY(sA[1], sB[1], sA[0], sB[0], true, ko + 128, WB8);
    KBODY(sA[2], sB[2], sA[1], sB[1], true, ko + 160, WB8);
    KBODY(sA[3], sB[3], sA[2], sB[2], true, ko + 192, WB8);
  }
  // t=28: stages T31 (the last tile). Tail drains 8 -> 4 -> 0.
  KBODY(sA[0], sB[0], sA[3], sB[3], true, 31 * 32, WB8);
  KBODY(sA[1], sB[1], sA[0], sB[0], false, 0, WB4);
  KBODY(sA[2], sB[2], sA[1], sB[1], false, 0, WB0);
  KBODY(sA[3], sB[3], sA[2], sB[2], false, 0, (void)0);

  // Epilogue: 32x32 C/D layout col = lane&31,
  // row = (reg&3) + 8*(reg>>2) + 4*(lane>>5)   [m74/m101, verified passing]
  const int cn = fr;
  const int rq = (lane >> 5) * 4;
#pragma unroll
  for (int ni = 0; ni < 2; ++ni) {
    const int col = bn * 256 + wc * 64 + ni * 32 + cn;
    const float bv = bias[col];
#pragma unroll
    for (int mi = 0; mi < 4; ++mi) {
      const int rowb = bm * 256 + wr * 128 + mi * 32 + rq;
      float* cp = C + (size_t)rowb * N_DIM + col;
#pragma unroll
      for (int reg = 0; reg < 16; ++reg) {
        const int roff = (reg & 3) + 8 * (reg >> 2);
        cp[(size_t)roff * N_DIM] = acc[mi][ni][reg] + bv;
      }
    }
  }
}

extern "C" void kernel_launch(void* const* d_in, const int* in_sizes, int n_in,
                              void* d_out, int out_size, void* d_ws, size_t ws_size,
                              hipStream_t stream) {
  const float* x      = (const float*)d_in[0];  // [4,4096,1024]
  const float* weight = (const float*)d_in[1];  // [4096,1024]
  const float* bias   = (const float*)d_in[2];  // [4096]
  const float* w1     = (const float*)d_in[3];  // [9,4096,32]
  const float* w2     = (const float*)d_in[4];  // [9,32,1024]
  const int* src_id   = (const int*)d_in[5];    // scalar
  const int* tgt_id   = (const int*)d_in[6];    // scalar
  float* out          = (float*)d_out;          // [4,4096,4096]

  // Workspace layout: x_f16 (32 MiB) | w_eff_f16 (8 MiB). Rewritten fully
  // every call (harness re-poisons d_ws).
  _Float16* xh   = (_Float16*)d_ws;
  _Float16* weff = xh + (size_t)M_DIM * K_DIM;

  prep_fused_kernel<<<CVT_BLOCKS + N_DIM, 256, 0, stream>>>(
      (const float4*)x, (h4*)xh, weight, w1, w2, src_id, tgt_id, (h4*)weff);

  lms_gemm256_kernel<<<dim3(1024), dim3(512), 0, stream>>>(xh, weff, bias, out);
}